// Round 11
// baseline (144.068 us; speedup 1.0000x reference)
//
#include <hip/hip_runtime.h>
#include <hip/hip_bf16.h>

// Causal SDPA, B=2 H=16 S=2048 D=64, fp32 in/out.
// R11: uniform-duration waves. Each wave owns TWO 32-row q-slices (qs=63-s
// heavy, then qs=s light): nt(63-s)+nt(s) = 33 for all s -> all 1024 waves
// identical length, zero drain (1024 waves = exactly 1/SIMD -> 512-VGPR
// budget). Fragment-major K/V (prep_frag) loaded straight to registers with
// kA/kB + vA/vB ping-pong (distance-2 prefetch) pinned by sched_barrier(0).
// No LDS, no barriers, no combine. Light pass re-reads L2-hot tiles.

#define S_ 2048
#define D_ 64
#define NBH 32

typedef __bf16 bf16x8 __attribute__((ext_vector_type(8)));
typedef float f32x16 __attribute__((ext_vector_type(16)));
typedef unsigned short u16x8 __attribute__((ext_vector_type(8)));
typedef unsigned int u32;
typedef u32 u32x4 __attribute__((ext_vector_type(4)));

static __device__ __forceinline__ unsigned short bfb(float f) {
    return __builtin_bit_cast(unsigned short, (__bf16)f);   // HW RNE cvt
}
static __device__ __forceinline__ u32 pk2(float lo, float hi) {
    return (u32)bfb(lo) | ((u32)bfb(hi) << 16);
}

// ---- prep: per (bh,t) 64x64 tile -> fragment-major bf16 K and V^T arrays.
// Kf unit u = h*256 + ks*64 + lane (lane=hi*32+lq), 16B each:
//   Kf[u] = K[bh][t*64 + h*32 + lq][8*(2ks+hi) .. +8]
//   Vf[u] = V[bh][t*64 + 8*(2ks+hi) .. +8][h*32 + lq]   (transposed)
__global__ __launch_bounds__(256)
void prep_frag(const float* __restrict__ K, const float* __restrict__ V,
               unsigned short* __restrict__ Kf, unsigned short* __restrict__ Vf) {
    const int bh = blockIdx.x >> 5;
    const int t  = blockIdx.x & 31;
    __shared__ float Ka[64][65];
    __shared__ float Va[64][65];
    const float* Ks = K + ((size_t)bh * S_ + t * 64) * D_;
    const float* Vs = V + ((size_t)bh * S_ + t * 64) * D_;
    #pragma unroll
    for (int i = 0; i < 4; ++i) {
        const int flat = i * 1024 + threadIdx.x * 4;
        const int s = flat >> 6, d = flat & 63;
        float4 kx = *reinterpret_cast<const float4*>(Ks + s * D_ + d);
        Ka[s][d] = kx.x; Ka[s][d+1] = kx.y; Ka[s][d+2] = kx.z; Ka[s][d+3] = kx.w;
        float4 vx = *reinterpret_cast<const float4*>(Vs + s * D_ + d);
        Va[s][d] = vx.x; Va[s][d+1] = vx.y; Va[s][d+2] = vx.z; Va[s][d+3] = vx.w;
    }
    __syncthreads();
    const size_t tb = ((size_t)bh * 32 + t) * 512;   // 16B-unit base
    #pragma unroll
    for (int i = 0; i < 2; ++i) {
        const int u  = i * 256 + threadIdx.x;
        const int h  = u >> 8, ks = (u >> 6) & 3, h2 = (u >> 5) & 1, l2 = u & 31;
        const int d0 = 8 * (2 * ks + h2);
        u16x8 ok, ov;
        #pragma unroll
        for (int j = 0; j < 8; ++j) {
            ok[j] = bfb(Ka[h * 32 + l2][d0 + j]);
            ov[j] = bfb(Va[d0 + j][h * 32 + l2]);
        }
        *reinterpret_cast<u16x8*>(Kf + (tb + u) * 8) = ok;
        *reinterpret_cast<u16x8*>(Vf + (tb + u) * 8) = ov;
    }
}

#define MFMA32(a, b, c) __builtin_amdgcn_mfma_f32_32x32x16_bf16((a), (b), (c), 0, 0, 0)

// Load all 8 fragments of one tile (4096 u16) — coalesced 1KB per instr.
#define LOADF(DST, BASE, T) { \
    const unsigned short* fb_ = (BASE) + (size_t)(T) * 4096 + lane * 8; \
    DST[0] = *reinterpret_cast<const bf16x8*>(fb_); \
    DST[1] = *reinterpret_cast<const bf16x8*>(fb_ + 512); \
    DST[2] = *reinterpret_cast<const bf16x8*>(fb_ + 1024); \
    DST[3] = *reinterpret_cast<const bf16x8*>(fb_ + 1536); \
    DST[4] = *reinterpret_cast<const bf16x8*>(fb_ + 2048); \
    DST[5] = *reinterpret_cast<const bf16x8*>(fb_ + 2560); \
    DST[6] = *reinterpret_cast<const bf16x8*>(fb_ + 3072); \
    DST[7] = *reinterpret_cast<const bf16x8*>(fb_ + 3584); }

#define PVSTEP(VX, KS, C, TL) { \
    u32 a0 = C[TL][0], a1 = C[TL][1], b0 = C[TL+1][0], b1 = C[TL+1][1]; \
    asm volatile("v_permlane32_swap_b32 %0, %1" : "+v"(a0), "+v"(b0)); \
    asm volatile("v_permlane32_swap_b32 %0, %1" : "+v"(a1), "+v"(b1)); \
    u32x4 w = { a0, a1, b0, b1 }; \
    bf16x8 pf = __builtin_bit_cast(bf16x8, w); \
    oa0 = MFMA32(VX[KS],     pf, oa0); \
    oa1 = MFMA32(VX[4 + KS], pf, oa1); }

// One 64-KV tile with buffers KX/VX; prefetches tile TPF into the SAME buffers
// (consumed two tiles later). sched_barrier(0) pins the load issue point.
#define TILE(KX, VX, T, TPF, NT) { \
    f32x16 s0, s1; \
    _Pragma("unroll") \
    for (int r = 0; r < 16; ++r) { s0[r] = 0.f; s1[r] = 0.f; } \
    __builtin_amdgcn_s_setprio(1); \
    _Pragma("unroll") \
    for (int ks = 0; ks < 4; ++ks) { \
        s0 = MFMA32(KX[ks],     qf[ks], s0); \
        s1 = MFMA32(KX[4 + ks], qf[ks], s1); \
    } \
    __builtin_amdgcn_s_setprio(0); \
    LOADF(KX, Kg, TPF) \
    __builtin_amdgcn_sched_barrier(0); \
    if ((T) == (NT) - 1) { \
        const int qg = q0w + lq - (T) * 64; \
        _Pragma("unroll") \
        for (int r = 0; r < 16; ++r) { \
            const int kv0 = (r & 3) + 8 * (r >> 2) + 4 * hi; \
            if (kv0 > qg)      s0[r] = -__builtin_inff(); \
            if (kv0 + 32 > qg) s1[r] = -__builtin_inff(); \
        } \
    } \
    float mx[16]; \
    _Pragma("unroll") \
    for (int r = 0; r < 16; ++r) mx[r] = fmaxf(s0[r], s1[r]); \
    _Pragma("unroll") \
    for (int off = 8; off >= 1; off >>= 1) \
        for (int r = 0; r < off; ++r) mx[r] = fmaxf(mx[r], mx[r + off]); \
    const float v = fmaxf(mx[0], __shfl_xor(mx[0], 32)); \
    if (__any(v > m_ + 8.0f ? 1 : 0)) { \
        const float mn = fmaxf(m_, v); \
        const float al = __builtin_amdgcn_exp2f(m_ - mn); \
        m_ = mn; \
        l_ *= al; \
        _Pragma("unroll") \
        for (int r = 0; r < 16; ++r) { oa0[r] *= al; oa1[r] *= al; } \
    } \
    _Pragma("unroll") \
    for (int r = 0; r < 16; ++r) { \
        s0[r] = __builtin_amdgcn_exp2f(s0[r] - m_); \
        s1[r] = __builtin_amdgcn_exp2f(s1[r] - m_); \
    } \
    { \
        float ts[16]; \
        _Pragma("unroll") \
        for (int r = 0; r < 16; ++r) ts[r] = s0[r] + s1[r]; \
        _Pragma("unroll") \
        for (int off = 8; off >= 1; off >>= 1) \
            for (int r = 0; r < off; ++r) ts[r] += ts[r + off]; \
        l_ += ts[0] + __shfl_xor(ts[0], 32); \
    } \
    u32 c0[4][2], c1[4][2]; \
    _Pragma("unroll") \
    for (int tq = 0; tq < 4; ++tq) { \
        c0[tq][0] = pk2(s0[4*tq+0], s0[4*tq+1]); \
        c0[tq][1] = pk2(s0[4*tq+2], s0[4*tq+3]); \
        c1[tq][0] = pk2(s1[4*tq+0], s1[4*tq+1]); \
        c1[tq][1] = pk2(s1[4*tq+2], s1[4*tq+3]); \
    } \
    __builtin_amdgcn_s_setprio(1); \
    PVSTEP(VX, 0, c0, 0) PVSTEP(VX, 1, c0, 2) PVSTEP(VX, 2, c1, 0) PVSTEP(VX, 3, c1, 2) \
    __builtin_amdgcn_s_setprio(0); \
    LOADF(VX, Vg, TPF) \
    __builtin_amdgcn_sched_barrier(0); \
}

__global__ __launch_bounds__(256, 1)
void attn_pair(const float* __restrict__ Q, const unsigned short* __restrict__ Kf,
               const unsigned short* __restrict__ Vf, float* __restrict__ O) {
    const int tid  = threadIdx.x;
    const int wq   = tid >> 6;
    const int lane = tid & 63;
    const int lq   = lane & 31;
    const int hi   = lane >> 5;

    const int bid = blockIdx.x;              // 256 blocks, 1/CU
    const int bh  = bid & 31;                // XCD x hosts bh%8==x (4 bh, ~4MB KV)
    const int sp  = (bid >> 5) * 4 + wq;     // 0..31: slice pair id

    const unsigned short* Kg = Kf + (size_t)bh * 131072;   // 32 tiles * 4096 u16
    const unsigned short* Vg = Vf + (size_t)bh * 131072;
    const float qscale = 0.18033688011112042f;   // log2(e)/8

    // Two passes per wave: heavy slice qs=63-sp, then light qs=sp.
    // nt(63-sp) + nt(sp) = 33 for all sp -> uniform wave duration.
    #pragma unroll
    for (int pass = 0; pass < 2; ++pass) {
        const int qs  = pass ? sp : (63 - sp);
        const int q0w = qs * 32;
        const int nt  = (qs >> 1) + 1;

        bf16x8 qf[4];
        {
            const float* qsrc = Q + ((size_t)bh * S_ + q0w + lq) * D_;
            #pragma unroll
            for (int ks = 0; ks < 4; ++ks) {
                const float* p = qsrc + ks * 16 + hi * 8;
                float4 x = *reinterpret_cast<const float4*>(p);
                float4 y = *reinterpret_cast<const float4*>(p + 4);
                union { unsigned short u[8]; bf16x8 v; } tt;
                tt.u[0] = bfb(x.x * qscale); tt.u[1] = bfb(x.y * qscale);
                tt.u[2] = bfb(x.z * qscale); tt.u[3] = bfb(x.w * qscale);
                tt.u[4] = bfb(y.x * qscale); tt.u[5] = bfb(y.y * qscale);
                tt.u[6] = bfb(y.z * qscale); tt.u[7] = bfb(y.w * qscale);
                qf[ks] = tt.v;
            }
        }

        f32x16 oa0, oa1;
        #pragma unroll
        for (int r = 0; r < 16; ++r) { oa0[r] = 0.f; oa1[r] = 0.f; }
        float m_ = -__builtin_inff(), l_ = 0.f;

        bf16x8 kA[8], kB[8], vA[8], vB[8];
        LOADF(kA, Kg, 0) LOADF(vA, Vg, 0)
        LOADF(kB, Kg, 1) LOADF(vB, Vg, 1)    // tiles 0..31 always exist
        __builtin_amdgcn_sched_barrier(0);

        // ping-pong: even tiles in kA/vA, odd in kB/vB; each TILE prefetches
        // t+2 into its own buffer (clamped to 31 -> in-bounds over-prefetch).
        for (int t = 0; t < nt; t += 2) {
            const int p0 = (t + 2 < 32) ? (t + 2) : 31;
            TILE(kA, vA, t, p0, nt)
            if (t + 1 < nt) {
                const int p1 = (t + 3 < 32) ? (t + 3) : 31;
                TILE(kB, vB, t + 1, p1, nt)
            }
        }

        // ---- epilogue: O[q][d] = O^T / l ; d = (r&3)+8*(r>>2)+4*hi (+32)
        const float inv = 1.0f / l_;
        float* Ob = O + ((size_t)bh * S_ + q0w + lq) * D_;
        #pragma unroll
        for (int g = 0; g < 4; ++g) {
            float4 o0 = { oa0[4*g+0]*inv, oa0[4*g+1]*inv, oa0[4*g+2]*inv, oa0[4*g+3]*inv };
            *reinterpret_cast<float4*>(&Ob[8*g + 4*hi]) = o0;
            float4 o1 = { oa1[4*g+0]*inv, oa1[4*g+1]*inv, oa1[4*g+2]*inv, oa1[4*g+3]*inv };
            *reinterpret_cast<float4*>(&Ob[32 + 8*g + 4*hi]) = o1;
        }
    }
}

extern "C" void kernel_launch(void* const* d_in, const int* in_sizes, int n_in,
                              void* d_out, int out_size, void* d_ws, size_t ws_size,
                              hipStream_t stream) {
    const float* Q = (const float*)d_in[0];
    const float* K = (const float*)d_in[1];
    const float* V = (const float*)d_in[2];
    // d_in[3] = mask: exact causal tril -> applied analytically.
    float* O = (float*)d_out;

    unsigned short* Kf = (unsigned short*)d_ws;                 // 8 MB
    unsigned short* Vf = Kf + (size_t)4194304;                  // 8 MB

    hipLaunchKernelGGL(prep_frag, dim3(1024), dim3(256), 0, stream, K, V, Kf, Vf);
    hipLaunchKernelGGL(attn_pair, dim3(256),  dim3(256), 0, stream, Q, Kf, Vf, O);
}